// Round 8
// baseline (282.477 us; speedup 1.0000x reference)
//
#include <hip/hip_runtime.h>
#include <math.h>
#include <stdint.h>

#define NTOT   8192
#define HALF_N 4096
#define DIM    512
#define INV_T  14.2857142857142857f   // 1/0.07
#define NBLK   512                    // 64 bi x 8 d-chunks (mod-64 bands)

using s16x8 = __attribute__((ext_vector_type(8))) short;
using f32x4 = __attribute__((ext_vector_type(4))) float;

// Scratch in static device globals (fully rewritten every call; no d_ws use).
__device__ unsigned short g_fnb[NTOT * DIM];   // normalized bf16 matrix, 8 MB
__device__ float g_pos[NTOT];
__device__ float g_sumexp[NTOT];
__device__ int   g_cnt[NTOT];
__device__ int   g_done;                       // last-block-finalize counter

__device__ __forceinline__ float bf2f(unsigned short u) {
  union { unsigned int i; float f; } v; v.i = ((unsigned int)u) << 16; return v.f;
}
__device__ __forceinline__ unsigned short f2bf(float x) {
  union { float f; unsigned int i; } v; v.f = x;
  unsigned int u = v.i;
  return (unsigned short)((u + 0x7FFFu + ((u >> 16) & 1u)) >> 16);
}

// ---------------- kernel 1: normalize pairs -> bf16, pos, zero stats ----------------
__global__ __launch_bounds__(256) void knorm(const float* __restrict__ f1,
                                             const float* __restrict__ f2) {
  const int tid  = threadIdx.x;
  const int wv   = tid >> 6;
  const int pi   = wv >> 1;            // pair within block
  const int half = wv & 1;             // 0: f1 row, 1: f2 row
  const int lane = tid & 63;
  const int b    = blockIdx.x * 2 + pi;
  const int row  = b + half * HALF_N;

  if (blockIdx.x == 0 && tid == 0) g_done = 0;
  if (tid < 4) {                       // zero the 4 stat rows this block owns
    const int r = blockIdx.x * 2 + (tid & 1) + (tid >> 1) * HALF_N;
    g_sumexp[r] = 0.f; g_cnt[r] = 0;
  }

  const float* src = (half == 0) ? (f1 + (size_t)b * DIM) : (f2 + (size_t)b * DIM);
  float4 v0 = ((const float4*)src)[lane];
  float4 v1 = ((const float4*)src)[lane + 64];
  float ss = v0.x*v0.x + v0.y*v0.y + v0.z*v0.z + v0.w*v0.w
           + v1.x*v1.x + v1.y*v1.y + v1.z*v1.z + v1.w*v1.w;
  #pragma unroll
  for (int o = 32; o >= 1; o >>= 1) ss += __shfl_xor(ss, o, 64);
  const float sc = 1.0f / fmaxf(sqrtf(ss), 1e-8f);
  ushort4 h0, h1;
  h0.x = f2bf(v0.x * sc); h0.y = f2bf(v0.y * sc);
  h0.z = f2bf(v0.z * sc); h0.w = f2bf(v0.w * sc);
  h1.x = f2bf(v1.x * sc); h1.y = f2bf(v1.y * sc);
  h1.z = f2bf(v1.z * sc); h1.w = f2bf(v1.w * sc);
  ushort4* dst = (ushort4*)(g_fnb + (size_t)row * DIM);
  dst[lane]      = h0;
  dst[lane + 64] = h1;

  // pos[b] = <fn_b, fn_{b+4096}> on the same bf16 values the GEMM uses
  __shared__ ushort4 sh[2][64][2];
  if (half == 1) { sh[pi][lane][0] = h0; sh[pi][lane][1] = h1; }
  __syncthreads();
  if (half == 0) {
    const ushort4 p0 = sh[pi][lane][0], p1 = sh[pi][lane][1];
    float s = bf2f(h0.x)*bf2f(p0.x) + bf2f(h0.y)*bf2f(p0.y)
            + bf2f(h0.z)*bf2f(p0.z) + bf2f(h0.w)*bf2f(p0.w)
            + bf2f(h1.x)*bf2f(p1.x) + bf2f(h1.y)*bf2f(p1.y)
            + bf2f(h1.z)*bf2f(p1.z) + bf2f(h1.w)*bf2f(p1.w);
    #pragma unroll
    for (int o = 32; o >= 1; o >>= 1) s += __shfl_xor(s, o, 64);
    if (lane == 0) { g_pos[b] = s; g_pos[b + HALF_N] = s; }
  }
}

// ---------------- kernel 2: mod-64 band GEMM + dual-sided reductions + finalize ----
// Block (bi, dc): row-tile bi, j-tiles jt=(bi+d)%64 for d=4dc..4dc+3 (+d=32 when
// dc==7 && bi<32). Every unordered tile pair once -> 2080 tiles in 512 blocks.
// R2's proven shape: BK=32, plain in-loop staging (compiler-scheduled), deep
// 64-80-step loop per block, 2 blocks/CU. Swizzle phys_cb=(cb+(row>>1))&3 puts
// every bank group at exactly 2 lanes -> conflict-free (2-way is free, m136).
__global__ __launch_bounds__(256, 3) void kmain(float* __restrict__ out) {
  __shared__ unsigned short As[128 * 32];
  __shared__ unsigned short Bs[128 * 32];

  const int b   = blockIdx.x;
  const int bi  = b >> 3;
  const int dc  = b & 7;
  const int ntl = (dc == 7 && bi < 32) ? 5 : 4;
  const int i0  = bi * 128;

  const int tid  = threadIdx.x;
  const int lane = tid & 63;
  const int w    = tid >> 6;
  const int wr   = (w >> 1) * 64;   // wave row base
  const int wc   = (w & 1) * 64;    // wave col base
  const int lrow = lane & 15;
  const int lq   = lane >> 4;

  // staging map (R2's): thread covers rows srow and srow+64, col block sc4
  const int srow = tid >> 2;        // 0..63
  const int sc4  = tid & 3;         // logical 8-short col block
  const unsigned short* Ag = g_fnb + (size_t)(i0 + srow) * DIM + sc4 * 8;
  // swizzled LDS write base; (srow+64)>>1 adds 32 -> &3 unchanged, so +64*32 works
  unsigned short* Aw = &As[srow * 32 + (((sc4 + (srow >> 1)) & 3) * 8)];
  unsigned short* Bw = &Bs[srow * 32 + (((sc4 + (srow >> 1)) & 3) * 8)];

  for (int t = 0; t < ntl; ++t) {
    const int d  = dc * 4 + t;
    const int jt = (bi + d) & 63;
    const int j0 = jt * 128;
    const bool offd = (d != 0);
    const unsigned short* Bg = g_fnb + (size_t)(j0 + srow) * DIM + sc4 * 8;

    f32x4 acc[4][4];
    #pragma unroll
    for (int a = 0; a < 4; ++a)
      #pragma unroll
      for (int bb = 0; bb < 4; ++bb) { acc[a][bb][0]=0.f; acc[a][bb][1]=0.f; acc[a][bb][2]=0.f; acc[a][bb][3]=0.f; }

    for (int kt = 0; kt < 16; ++kt) {
      const int kb = kt * 32;
      __syncthreads();                   // prev step's LDS reads done
      *(int4*)(Aw)           = *(const int4*)(Ag + kb);
      *(int4*)(Aw + 64 * 32) = *(const int4*)(Ag + (size_t)64 * DIM + kb);
      if (offd) {
        *(int4*)(Bw)           = *(const int4*)(Bg + kb);
        *(int4*)(Bw + 64 * 32) = *(const int4*)(Bg + (size_t)64 * DIM + kb);
      }
      __syncthreads();                   // tile kt visible

      const unsigned short* Bsrc = offd ? (const unsigned short*)Bs
                                        : (const unsigned short*)As;
      s16x8 af[4], bf[4];
      #pragma unroll
      for (int mi = 0; mi < 4; ++mi) {
        const int r = wr + mi * 16 + lrow;
        af[mi] = *(const s16x8*)(&As[r * 32 + (((lq + (r >> 1)) & 3) * 8)]);
      }
      #pragma unroll
      for (int ni = 0; ni < 4; ++ni) {
        const int r = wc + ni * 16 + lrow;
        bf[ni] = *(const s16x8*)(&Bsrc[r * 32 + (((lq + (r >> 1)) & 3) * 8)]);
      }
      #pragma unroll
      for (int mi = 0; mi < 4; ++mi)
        #pragma unroll
        for (int ni = 0; ni < 4; ++ni)
          acc[mi][ni] = __builtin_amdgcn_mfma_f32_16x16x32_bf16(af[mi], bf[ni], acc[mi][ni], 0, 0, 0);
    }

    // ---- per-tile epilogue (R7-verified). C: col = lane&15, row = lq*4+reg.
    #pragma unroll
    for (int mi = 0; mi < 4; ++mi) {          // row side (always)
      #pragma unroll
      for (int r = 0; r < 4; ++r) {
        const int i  = i0 + wr + mi * 16 + lq * 4 + r;
        const float pv = g_pos[i];
        float sx = 0.f; int c = 0;
        #pragma unroll
        for (int ni = 0; ni < 4; ++ni) {
          const int j = j0 + wc + ni * 16 + lrow;
          const float v = acc[mi][ni][r];
          const float e = __expf(v * INV_T);
          const bool diag = (j == i);
          sx += diag ? 0.f : e;
          c += (!diag && (j != (i ^ HALF_N)) && (v > pv)) ? 1 : 0;
        }
        #pragma unroll
        for (int o = 1; o < 16; o <<= 1) {
          sx += __shfl_xor(sx, o, 64);
          c  += __shfl_xor(c, o, 64);
        }
        if (lrow == 0) {
          atomicAdd(&g_sumexp[i], sx);
          atomicAdd(&g_cnt[i], c);
        }
      }
    }

    if (offd) {                               // col side (disjoint slabs)
      #pragma unroll
      for (int ni = 0; ni < 4; ++ni) {
        const int j  = j0 + wc + ni * 16 + lrow;
        const float pj = g_pos[j];
        float sx = 0.f; int c = 0;
        #pragma unroll
        for (int mi = 0; mi < 4; ++mi) {
          #pragma unroll
          for (int r = 0; r < 4; ++r) {
            const int i = i0 + wr + mi * 16 + lq * 4 + r;
            const float v = acc[mi][ni][r];
            sx += __expf(v * INV_T);
            c += ((i != (j ^ HALF_N)) && (v > pj)) ? 1 : 0;
          }
        }
        sx += __shfl_xor(sx, 16, 64); sx += __shfl_xor(sx, 32, 64);
        c  += __shfl_xor(c, 16, 64);  c  += __shfl_xor(c, 32, 64);
        if (lq == 0) {
          atomicAdd(&g_sumexp[j], sx);
          atomicAdd(&g_cnt[j], c);
        }
      }
    }
  }

  // ---- last-block finalize (R6/R7-validated) ----
  __threadfence();
  __shared__ int s_last;
  if (tid == 0) s_last = (atomicAdd(&g_done, 1) == NBLK - 1);
  __syncthreads();
  if (s_last) {
    float nll = 0.f, t1 = 0.f, t5 = 0.f, mr = 0.f;
    for (int i = tid; i < NTOT; i += 256) {
      const float se = __hip_atomic_load(&g_sumexp[i], __ATOMIC_RELAXED,
                                         __HIP_MEMORY_SCOPE_AGENT);
      const int  c  = __hip_atomic_load(&g_cnt[i], __ATOMIC_RELAXED,
                                        __HIP_MEMORY_SCOPE_AGENT);
      nll += -g_pos[i] * INV_T + logf(se);
      t1 += (c == 0) ? 1.f : 0.f;
      t5 += (c < 5) ? 1.f : 0.f;
      mr += (float)c;
    }
    #pragma unroll
    for (int o = 32; o >= 1; o >>= 1) {
      nll += __shfl_xor(nll, o, 64);
      t1  += __shfl_xor(t1, o, 64);
      t5  += __shfl_xor(t5, o, 64);
      mr  += __shfl_xor(mr, o, 64);
    }
    __shared__ float red[4][4];
    if ((tid & 63) == 0) {
      red[tid >> 6][0] = nll; red[tid >> 6][1] = t1;
      red[tid >> 6][2] = t5;  red[tid >> 6][3] = mr;
    }
    __syncthreads();
    if (tid == 0) {
      float a = 0.f, bq = 0.f, c = 0.f, dd = 0.f;
      for (int k = 0; k < 4; ++k) { a += red[k][0]; bq += red[k][1]; c += red[k][2]; dd += red[k][3]; }
      out[0] = a / (float)NTOT;
      out[1] = bq / (float)NTOT;
      out[2] = c / (float)NTOT;
      out[3] = 1.f + dd / (float)NTOT;
    }
  }
}

extern "C" void kernel_launch(void* const* d_in, const int* in_sizes, int n_in,
                              void* d_out, int out_size, void* d_ws, size_t ws_size,
                              hipStream_t stream) {
  const float* f1 = (const float*)d_in[0];
  const float* f2 = (const float*)d_in[1];
  float* out = (float*)d_out;

  knorm<<<dim3(2048), dim3(256), 0, stream>>>(f1, f2);
  kmain<<<dim3(NBLK), dim3(256), 0, stream>>>(out);
}

// Round 9
// 262.127 us; speedup vs baseline: 1.0776x; 1.0776x over previous
//
#include <hip/hip_runtime.h>
#include <math.h>
#include <stdint.h>

#define NTOT   8192
#define HALF_N 4096
#define DIM    512
#define INV_T  14.2857142857142857f   // 1/0.07
#define NBLK   1040                   // 2080 tiles / 2 per block, all-static bands

using s16x8 = __attribute__((ext_vector_type(8))) short;
using f32x4 = __attribute__((ext_vector_type(4))) float;

// Scratch in static device globals (fully rewritten every call; no d_ws use).
__device__ unsigned short g_fnb[NTOT * DIM];   // normalized bf16 matrix, 8 MB
__device__ float g_pos[NTOT];
__device__ float g_sumexp[NTOT];
__device__ int   g_cnt[NTOT];
__device__ int   g_done;                       // last-block-finalize counter

__device__ __forceinline__ float bf2f(unsigned short u) {
  union { unsigned int i; float f; } v; v.i = ((unsigned int)u) << 16; return v.f;
}
__device__ __forceinline__ unsigned short f2bf(float x) {
  union { float f; unsigned int i; } v; v.f = x;
  unsigned int u = v.i;
  return (unsigned short)((u + 0x7FFFu + ((u >> 16) & 1u)) >> 16);
}

// ---------------- kernel 1: normalize pairs -> bf16, pos, zero stats ----------------
__global__ __launch_bounds__(256) void knorm(const float* __restrict__ f1,
                                             const float* __restrict__ f2) {
  const int tid  = threadIdx.x;
  const int wv   = tid >> 6;
  const int pi   = wv >> 1;            // pair within block
  const int half = wv & 1;             // 0: f1 row, 1: f2 row
  const int lane = tid & 63;
  const int b    = blockIdx.x * 2 + pi;
  const int row  = b + half * HALF_N;

  if (blockIdx.x == 0 && tid == 0) g_done = 0;
  if (tid < 4) {                       // zero the 4 stat rows this block owns
    const int r = blockIdx.x * 2 + (tid & 1) + (tid >> 1) * HALF_N;
    g_sumexp[r] = 0.f; g_cnt[r] = 0;
  }

  const float* src = (half == 0) ? (f1 + (size_t)b * DIM) : (f2 + (size_t)b * DIM);
  float4 v0 = ((const float4*)src)[lane];
  float4 v1 = ((const float4*)src)[lane + 64];
  float ss = v0.x*v0.x + v0.y*v0.y + v0.z*v0.z + v0.w*v0.w
           + v1.x*v1.x + v1.y*v1.y + v1.z*v1.z + v1.w*v1.w;
  #pragma unroll
  for (int o = 32; o >= 1; o >>= 1) ss += __shfl_xor(ss, o, 64);
  const float sc = 1.0f / fmaxf(sqrtf(ss), 1e-8f);
  ushort4 h0, h1;
  h0.x = f2bf(v0.x * sc); h0.y = f2bf(v0.y * sc);
  h0.z = f2bf(v0.z * sc); h0.w = f2bf(v0.w * sc);
  h1.x = f2bf(v1.x * sc); h1.y = f2bf(v1.y * sc);
  h1.z = f2bf(v1.z * sc); h1.w = f2bf(v1.w * sc);
  ushort4* dst = (ushort4*)(g_fnb + (size_t)row * DIM);
  dst[lane]      = h0;
  dst[lane + 64] = h1;

  // pos[b] = <fn_b, fn_{b+4096}> on the same bf16 values the GEMM uses
  __shared__ ushort4 sh[2][64][2];
  if (half == 1) { sh[pi][lane][0] = h0; sh[pi][lane][1] = h1; }
  __syncthreads();
  if (half == 0) {
    const ushort4 p0 = sh[pi][lane][0], p1 = sh[pi][lane][1];
    float s = bf2f(h0.x)*bf2f(p0.x) + bf2f(h0.y)*bf2f(p0.y)
            + bf2f(h0.z)*bf2f(p0.z) + bf2f(h0.w)*bf2f(p0.w)
            + bf2f(h1.x)*bf2f(p1.x) + bf2f(h1.y)*bf2f(p1.y)
            + bf2f(h1.z)*bf2f(p1.z) + bf2f(h1.w)*bf2f(p1.w);
    #pragma unroll
    for (int o = 32; o >= 1; o >>= 1) s += __shfl_xor(s, o, 64);
    if (lane == 0) { g_pos[b] = s; g_pos[b + HALF_N] = s; }
  }
}

// ---------------- kernel 2: static-band triangular GEMM + reductions + finalize ----
// 1040 blocks x exactly 2 tiles x 16 kt — ALL loop bounds compile-time constant,
// staging unconditional (B staged even on diagonal tiles) so the compiler can
// unroll + software-pipeline like R2/m97. Hypothesis H: runtime bounds and
// branchy staging were what killed R5/R7/R8.
// Bands: b<64: (bi=b, d=t); 64<=b<1024: (bi=(b-64)&63, d=2+2*((b-64)>>6)+t);
// b>=1024: d=32, bi=2*(b-1024)+t. Covers all 2080 unordered tile pairs once.
// LDS swizzle phys_cb=(cb+(row>>1))&3: measured 0 conflicts (R8).
__global__ __launch_bounds__(256, 3) void kmain(float* __restrict__ out) {
  __shared__ unsigned short As[128 * 32];
  __shared__ unsigned short Bs[128 * 32];

  const int b = blockIdx.x;

  const int tid  = threadIdx.x;
  const int lane = tid & 63;
  const int w    = tid >> 6;
  const int wr   = (w >> 1) * 64;   // wave row base
  const int wc   = (w & 1) * 64;    // wave col base
  const int lrow = lane & 15;
  const int lq   = lane >> 4;

  // staging map: thread covers rows srow and srow+64, logical col block sc4
  const int srow = tid >> 2;        // 0..63
  const int sc4  = tid & 3;
  unsigned short* Aw = &As[srow * 32 + (((sc4 + (srow >> 1)) & 3) * 8)];
  unsigned short* Bw = &Bs[srow * 32 + (((sc4 + (srow >> 1)) & 3) * 8)];

  for (int t = 0; t < 2; ++t) {                 // constant trip count
    int bi_t, d;
    if (b >= 1024)      { bi_t = (b - 1024) * 2 + t; d = 32; }
    else if (b >= 64)   { bi_t = (b - 64) & 63; d = 2 + (((b - 64) >> 6) << 1) + t; }
    else                { bi_t = b; d = t; }
    const int jt = (bi_t + d) & 63;
    const int i0 = bi_t * 128;
    const int j0 = jt * 128;

    const unsigned short* Ag = g_fnb + (size_t)(i0 + srow) * DIM + sc4 * 8;
    const unsigned short* Bg = g_fnb + (size_t)(j0 + srow) * DIM + sc4 * 8;

    f32x4 acc[4][4];
    #pragma unroll
    for (int a = 0; a < 4; ++a)
      #pragma unroll
      for (int bb = 0; bb < 4; ++bb) { acc[a][bb][0]=0.f; acc[a][bb][1]=0.f; acc[a][bb][2]=0.f; acc[a][bb][3]=0.f; }

    for (int kt = 0; kt < 16; ++kt) {           // constant trip count
      const int kb = kt * 32;
      __syncthreads();                          // prev step's LDS reads done
      *(int4*)(Aw)           = *(const int4*)(Ag + kb);
      *(int4*)(Aw + 64 * 32) = *(const int4*)(Ag + (size_t)64 * DIM + kb);
      *(int4*)(Bw)           = *(const int4*)(Bg + kb);
      *(int4*)(Bw + 64 * 32) = *(const int4*)(Bg + (size_t)64 * DIM + kb);
      __syncthreads();                          // tile kt visible

      s16x8 af[4], bf[4];
      #pragma unroll
      for (int mi = 0; mi < 4; ++mi) {
        const int r = wr + mi * 16 + lrow;
        af[mi] = *(const s16x8*)(&As[r * 32 + (((lq + (r >> 1)) & 3) * 8)]);
      }
      #pragma unroll
      for (int ni = 0; ni < 4; ++ni) {
        const int r = wc + ni * 16 + lrow;
        bf[ni] = *(const s16x8*)(&Bs[r * 32 + (((lq + (r >> 1)) & 3) * 8)]);
      }
      #pragma unroll
      for (int mi = 0; mi < 4; ++mi)
        #pragma unroll
        for (int ni = 0; ni < 4; ++ni)
          acc[mi][ni] = __builtin_amdgcn_mfma_f32_16x16x32_bf16(af[mi], bf[ni], acc[mi][ni], 0, 0, 0);
    }

    // ---- per-tile epilogue. C: col = lane&15, row = lq*4+reg (verified).
    #pragma unroll
    for (int mi = 0; mi < 4; ++mi) {            // row side (always)
      #pragma unroll
      for (int r = 0; r < 4; ++r) {
        const int i  = i0 + wr + mi * 16 + lq * 4 + r;
        const float pv = g_pos[i];
        float sx = 0.f; int c = 0;
        #pragma unroll
        for (int ni = 0; ni < 4; ++ni) {
          const int j = j0 + wc + ni * 16 + lrow;
          const float v = acc[mi][ni][r];
          const float e = __expf(v * INV_T);
          const bool diag = (j == i);
          sx += diag ? 0.f : e;
          c += (!diag && (j != (i ^ HALF_N)) && (v > pv)) ? 1 : 0;
        }
        #pragma unroll
        for (int o = 1; o < 16; o <<= 1) {
          sx += __shfl_xor(sx, o, 64);
          c  += __shfl_xor(c, o, 64);
        }
        if (lrow == 0) {
          atomicAdd(&g_sumexp[i], sx);
          atomicAdd(&g_cnt[i], c);
        }
      }
    }

    if (d != 0) {                               // col side (disjoint slabs)
      #pragma unroll
      for (int ni = 0; ni < 4; ++ni) {
        const int j  = j0 + wc + ni * 16 + lrow;
        const float pj = g_pos[j];
        float sx = 0.f; int c = 0;
        #pragma unroll
        for (int mi = 0; mi < 4; ++mi) {
          #pragma unroll
          for (int r = 0; r < 4; ++r) {
            const int i = i0 + wr + mi * 16 + lq * 4 + r;
            const float v = acc[mi][ni][r];
            sx += __expf(v * INV_T);
            c += ((i != (j ^ HALF_N)) && (v > pj)) ? 1 : 0;
          }
        }
        sx += __shfl_xor(sx, 16, 64); sx += __shfl_xor(sx, 32, 64);
        c  += __shfl_xor(c, 16, 64);  c  += __shfl_xor(c, 32, 64);
        if (lq == 0) {
          atomicAdd(&g_sumexp[j], sx);
          atomicAdd(&g_cnt[j], c);
        }
      }
    }
  }

  // ---- last-block finalize (validated R6-R8) ----
  __threadfence();
  __shared__ int s_last;
  if (tid == 0) s_last = (atomicAdd(&g_done, 1) == NBLK - 1);
  __syncthreads();
  if (s_last) {
    float nll = 0.f, t1 = 0.f, t5 = 0.f, mr = 0.f;
    for (int i = tid; i < NTOT; i += 256) {
      const float se = __hip_atomic_load(&g_sumexp[i], __ATOMIC_RELAXED,
                                         __HIP_MEMORY_SCOPE_AGENT);
      const int  c  = __hip_atomic_load(&g_cnt[i], __ATOMIC_RELAXED,
                                        __HIP_MEMORY_SCOPE_AGENT);
      nll += -g_pos[i] * INV_T + logf(se);
      t1 += (c == 0) ? 1.f : 0.f;
      t5 += (c < 5) ? 1.f : 0.f;
      mr += (float)c;
    }
    #pragma unroll
    for (int o = 32; o >= 1; o >>= 1) {
      nll += __shfl_xor(nll, o, 64);
      t1  += __shfl_xor(t1, o, 64);
      t5  += __shfl_xor(t5, o, 64);
      mr  += __shfl_xor(mr, o, 64);
    }
    __shared__ float red[4][4];
    if ((tid & 63) == 0) {
      red[tid >> 6][0] = nll; red[tid >> 6][1] = t1;
      red[tid >> 6][2] = t5;  red[tid >> 6][3] = mr;
    }
    __syncthreads();
    if (tid == 0) {
      float a = 0.f, bq = 0.f, c = 0.f, dd = 0.f;
      for (int k = 0; k < 4; ++k) { a += red[k][0]; bq += red[k][1]; c += red[k][2]; dd += red[k][3]; }
      out[0] = a / (float)NTOT;
      out[1] = bq / (float)NTOT;
      out[2] = c / (float)NTOT;
      out[3] = 1.f + dd / (float)NTOT;
    }
  }
}

extern "C" void kernel_launch(void* const* d_in, const int* in_sizes, int n_in,
                              void* d_out, int out_size, void* d_ws, size_t ws_size,
                              hipStream_t stream) {
  const float* f1 = (const float*)d_in[0];
  const float* f2 = (const float*)d_in[1];
  float* out = (float*)d_out;

  knorm<<<dim3(2048), dim3(256), 0, stream>>>(f1, f2);
  kmain<<<dim3(NBLK), dim3(256), 0, stream>>>(out);
}

// Round 10
// 230.920 us; speedup vs baseline: 1.2233x; 1.1351x over previous
//
#include <hip/hip_runtime.h>
#include <math.h>
#include <stdint.h>

#define NTOT   8192
#define HALF_N 4096
#define DIM    512
#define INV_T  14.2857142857142857f   // 1/0.07
#define NBLK   512                    // R2's grid: 64 bi x 8 j-chunks (full matrix)

using s16x8 = __attribute__((ext_vector_type(8))) short;
using f32x4 = __attribute__((ext_vector_type(4))) float;

// Scratch in static device globals (fully rewritten every call; no d_ws use).
__device__ unsigned short g_fnb[NTOT * DIM];   // normalized bf16 matrix, 8 MB
__device__ float g_pos[NTOT];
__device__ float g_sumexp[NTOT];
__device__ int   g_cnt[NTOT];
__device__ int   g_done;                       // last-block-finalize counter

__device__ __forceinline__ float bf2f(unsigned short u) {
  union { unsigned int i; float f; } v; v.i = ((unsigned int)u) << 16; return v.f;
}
__device__ __forceinline__ unsigned short f2bf(float x) {
  union { float f; unsigned int i; } v; v.f = x;
  unsigned int u = v.i;
  return (unsigned short)((u + 0x7FFFu + ((u >> 16) & 1u)) >> 16);
}

// ---------------- kernel 1: normalize pairs -> bf16, pos, zero stats ----------------
__global__ __launch_bounds__(256) void knorm(const float* __restrict__ f1,
                                             const float* __restrict__ f2) {
  const int tid  = threadIdx.x;
  const int wv   = tid >> 6;
  const int pi   = wv >> 1;            // pair within block
  const int half = wv & 1;             // 0: f1 row, 1: f2 row
  const int lane = tid & 63;
  const int b    = blockIdx.x * 2 + pi;
  const int row  = b + half * HALF_N;

  if (blockIdx.x == 0 && tid == 0) g_done = 0;
  if (tid < 4) {                       // zero the 4 stat rows this block owns
    const int r = blockIdx.x * 2 + (tid & 1) + (tid >> 1) * HALF_N;
    g_sumexp[r] = 0.f; g_cnt[r] = 0;
  }

  const float* src = (half == 0) ? (f1 + (size_t)b * DIM) : (f2 + (size_t)b * DIM);
  float4 v0 = ((const float4*)src)[lane];
  float4 v1 = ((const float4*)src)[lane + 64];
  float ss = v0.x*v0.x + v0.y*v0.y + v0.z*v0.z + v0.w*v0.w
           + v1.x*v1.x + v1.y*v1.y + v1.z*v1.z + v1.w*v1.w;
  #pragma unroll
  for (int o = 32; o >= 1; o >>= 1) ss += __shfl_xor(ss, o, 64);
  const float sc = 1.0f / fmaxf(sqrtf(ss), 1e-8f);
  ushort4 h0, h1;
  h0.x = f2bf(v0.x * sc); h0.y = f2bf(v0.y * sc);
  h0.z = f2bf(v0.z * sc); h0.w = f2bf(v0.w * sc);
  h1.x = f2bf(v1.x * sc); h1.y = f2bf(v1.y * sc);
  h1.z = f2bf(v1.z * sc); h1.w = f2bf(v1.w * sc);
  ushort4* dst = (ushort4*)(g_fnb + (size_t)row * DIM);
  dst[lane]      = h0;
  dst[lane + 64] = h1;

  // pos[b] = <fn_b, fn_{b+4096}> on the same bf16 values the GEMM uses
  __shared__ ushort4 sh[2][64][2];
  if (half == 1) { sh[pi][lane][0] = h0; sh[pi][lane][1] = h1; }
  __syncthreads();
  if (half == 0) {
    const ushort4 p0 = sh[pi][lane][0], p1 = sh[pi][lane][1];
    float s = bf2f(h0.x)*bf2f(p0.x) + bf2f(h0.y)*bf2f(p0.y)
            + bf2f(h0.z)*bf2f(p0.z) + bf2f(h0.w)*bf2f(p0.w)
            + bf2f(h1.x)*bf2f(p1.x) + bf2f(h1.y)*bf2f(p1.y)
            + bf2f(h1.z)*bf2f(p1.z) + bf2f(h1.w)*bf2f(p1.w);
    #pragma unroll
    for (int o = 32; o >= 1; o >>= 1) s += __shfl_xor(s, o, 64);
    if (lane == 0) { g_pos[b] = s; g_pos[b + HALF_N] = s; }
  }
}

// ---------------- kernel 2: LITERAL R2 kmain + one change (conflict-free swizzle) ----
// R2 measured 153 us with this exact structure (grid 64x8, 8-jt slab, BK=32,
// plain in-loop staging, per-jt row-side epilogue). The ONLY K-loop change vs R2:
// LDS physical col block = (cb + (row>>1)) & 3 on both write and read — R8-verified
// zero conflicts + correct results. R2's straight layout showed 8.4M conflict cycles
// (8-way aliasing on the b128 fragment reads).
// Controlled experiment: isolates the conflict-fix delta on the known-good baseline.
__global__ __launch_bounds__(256, 2) void kmain(float* __restrict__ out) {
  __shared__ unsigned short As[128 * 32];
  __shared__ unsigned short Bs[128 * 32];

  const int tid  = threadIdx.x;
  const int lane = tid & 63;
  const int w    = tid >> 6;
  const int bi   = blockIdx.x >> 3;
  const int bj   = blockIdx.x & 7;
  const int i0   = bi * 128;
  const int j0c  = bj * 1024;

  const int wr   = (w >> 1) * 64;   // wave row base within 128-tile
  const int wc   = (w & 1) * 64;    // wave col base
  const int lrow = lane & 15;
  const int lq   = lane >> 4;

  // pos values for the 16 rows this lane owns in C fragments (as in R2)
  float posv[4][4];
  #pragma unroll
  for (int mi = 0; mi < 4; ++mi)
    #pragma unroll
    for (int r = 0; r < 4; ++r)
      posv[mi][r] = g_pos[i0 + wr + mi * 16 + lq * 4 + r];

  float se[4][4];
  int   ct[4][4];
  #pragma unroll
  for (int mi = 0; mi < 4; ++mi)
    #pragma unroll
    for (int r = 0; r < 4; ++r) { se[mi][r] = 0.f; ct[mi][r] = 0; }

  // staging map (R2's): thread stages rows (tid>>2) and (tid>>2)+64,
  // logical 8-short col block (tid&3); swizzled physical block.
  const int srow = tid >> 2;
  const int sc4  = tid & 3;
  unsigned short* Aw = &As[srow * 32 + (((sc4 + (srow >> 1)) & 3) * 8)];
  unsigned short* Bw = &Bs[srow * 32 + (((sc4 + (srow >> 1)) & 3) * 8)];
  const unsigned short* Ag = g_fnb + (size_t)(i0 + srow) * DIM + sc4 * 8;

  for (int jt = 0; jt < 8; ++jt) {
    const int j0 = j0c + jt * 128;
    const unsigned short* Bg = g_fnb + (size_t)(j0 + srow) * DIM + sc4 * 8;

    f32x4 acc[4][4];
    #pragma unroll
    for (int a = 0; a < 4; ++a)
      #pragma unroll
      for (int b = 0; b < 4; ++b) { acc[a][b][0]=0.f; acc[a][b][1]=0.f; acc[a][b][2]=0.f; acc[a][b][3]=0.f; }

    for (int kt = 0; kt < 16; ++kt) {
      const int kb = kt * 32;
      __syncthreads();
      *(int4*)(Aw)           = *(const int4*)(Ag + kb);
      *(int4*)(Aw + 64 * 32) = *(const int4*)(Ag + (size_t)64 * DIM + kb);
      *(int4*)(Bw)           = *(const int4*)(Bg + kb);
      *(int4*)(Bw + 64 * 32) = *(const int4*)(Bg + (size_t)64 * DIM + kb);
      __syncthreads();

      s16x8 af[4], bf[4];
      #pragma unroll
      for (int mi = 0; mi < 4; ++mi) {
        const int r = wr + mi * 16 + lrow;
        af[mi] = *(const s16x8*)(&As[r * 32 + (((lq + (r >> 1)) & 3) * 8)]);
      }
      #pragma unroll
      for (int ni = 0; ni < 4; ++ni) {
        const int r = wc + ni * 16 + lrow;
        bf[ni] = *(const s16x8*)(&Bs[r * 32 + (((lq + (r >> 1)) & 3) * 8)]);
      }
      #pragma unroll
      for (int mi = 0; mi < 4; ++mi)
        #pragma unroll
        for (int ni = 0; ni < 4; ++ni)
          acc[mi][ni] = __builtin_amdgcn_mfma_f32_16x16x32_bf16(af[mi], bf[ni], acc[mi][ni], 0, 0, 0);
    }

    // epilogue: fold this j-tile into per-row partials (exactly R2's)
    #pragma unroll
    for (int mi = 0; mi < 4; ++mi) {
      #pragma unroll
      for (int ni = 0; ni < 4; ++ni) {
        const int j = j0 + wc + ni * 16 + lrow;   // C col = lane&15
        #pragma unroll
        for (int r = 0; r < 4; ++r) {
          const int i = i0 + wr + mi * 16 + lq * 4 + r;  // C row = quad*4+reg
          const float c = acc[mi][ni][r];
          float e = __expf(c * INV_T);
          const bool diag = (j == i);
          if (diag) e = 0.f;
          se[mi][r] += e;
          if (!diag && (j != (i ^ HALF_N)) && (c > posv[mi][r])) ct[mi][r]++;
        }
      }
    }
  }

  // reduce across the 16 lanes of each quad-row group, one atomic per row (R2's)
  #pragma unroll
  for (int mi = 0; mi < 4; ++mi) {
    #pragma unroll
    for (int r = 0; r < 4; ++r) {
      float s = se[mi][r];
      int   c = ct[mi][r];
      #pragma unroll
      for (int o = 1; o < 16; o <<= 1) {
        s += __shfl_xor(s, o, 64);
        c += __shfl_xor(c, o, 64);
      }
      if (lrow == 0) {
        const int i = i0 + wr + mi * 16 + lq * 4 + r;
        atomicAdd(&g_sumexp[i], s);
        atomicAdd(&g_cnt[i], c);
      }
    }
  }

  // ---- last-block finalize (validated R5-R9) ----
  __threadfence();
  __shared__ int s_last;
  if (tid == 0) s_last = (atomicAdd(&g_done, 1) == NBLK - 1);
  __syncthreads();
  if (s_last) {
    float nll = 0.f, t1 = 0.f, t5 = 0.f, mr = 0.f;
    for (int i = tid; i < NTOT; i += 256) {
      const float sev = __hip_atomic_load(&g_sumexp[i], __ATOMIC_RELAXED,
                                          __HIP_MEMORY_SCOPE_AGENT);
      const int  c  = __hip_atomic_load(&g_cnt[i], __ATOMIC_RELAXED,
                                        __HIP_MEMORY_SCOPE_AGENT);
      nll += -g_pos[i] * INV_T + logf(sev);
      t1 += (c == 0) ? 1.f : 0.f;
      t5 += (c < 5) ? 1.f : 0.f;
      mr += (float)c;
    }
    #pragma unroll
    for (int o = 32; o >= 1; o >>= 1) {
      nll += __shfl_xor(nll, o, 64);
      t1  += __shfl_xor(t1, o, 64);
      t5  += __shfl_xor(t5, o, 64);
      mr  += __shfl_xor(mr, o, 64);
    }
    __shared__ float red[4][4];
    if ((tid & 63) == 0) {
      red[tid >> 6][0] = nll; red[tid >> 6][1] = t1;
      red[tid >> 6][2] = t5;  red[tid >> 6][3] = mr;
    }
    __syncthreads();
    if (tid == 0) {
      float a = 0.f, bq = 0.f, c = 0.f, dd = 0.f;
      for (int k = 0; k < 4; ++k) { a += red[k][0]; bq += red[k][1]; c += red[k][2]; dd += red[k][3]; }
      out[0] = a / (float)NTOT;
      out[1] = bq / (float)NTOT;
      out[2] = c / (float)NTOT;
      out[3] = 1.f + dd / (float)NTOT;
    }
  }
}

extern "C" void kernel_launch(void* const* d_in, const int* in_sizes, int n_in,
                              void* d_out, int out_size, void* d_ws, size_t ws_size,
                              hipStream_t stream) {
  const float* f1 = (const float*)d_in[0];
  const float* f2 = (const float*)d_in[1];
  float* out = (float*)d_out;

  knorm<<<dim3(2048), dim3(256), 0, stream>>>(f1, f2);
  kmain<<<dim3(NBLK), dim3(256), 0, stream>>>(out);
}